// Round 18
// baseline (2072.967 us; speedup 1.0000x reference)
//
#include <hip/hip_runtime.h>
#include <stdint.h>

typedef _Float16 f16;
typedef _Float16 f16x8 __attribute__((ext_vector_type(8)));
typedef float f32x4 __attribute__((ext_vector_type(4)));

#define NROWS 16384
#define DIM   512
#define NEXP  8
#define BM    128
#define BN    128
#define BK    32
#define NKS   16
#define WSTRIDE (DIM*DIM)

#define GLOAD16(gp, lp) __builtin_amdgcn_global_load_lds( \
    (const __attribute__((address_space(1))) void*)(gp),  \
    (__attribute__((address_space(3))) void*)(lp), 16, 0, 0)

#define MFMA16(a,b,c) __builtin_amdgcn_mfma_f32_16x16x32_f16(a, b, c, 0, 0, 0)

#define WAITV(N) asm volatile("s_waitcnt vmcnt(" #N ")" ::: "memory")

// ---------- prep: W[l][e][i][o] fp32 -> Wt[l][e][o][i] fp16 ----------
__global__ __launch_bounds__(256) void convert_w(
    const float* __restrict__ w0, const float* __restrict__ w1,
    const float* __restrict__ w2, const float* __restrict__ wo,
    f16* __restrict__ Wt)
{
    __shared__ float tile[32][33];
    int b  = blockIdx.x;
    int m  = b >> 8;
    int bi = (b >> 4) & 15;
    int bj = b & 15;
    int layer = m >> 3;
    const float* src =
        (layer == 0 ? w0 : layer == 1 ? w1 : layer == 2 ? w2 : wo)
        + (size_t)(m & 7) * DIM * DIM;
    f16* dst = Wt + (size_t)m * DIM * DIM;
    int tx = threadIdx.x & 31, ty = threadIdx.x >> 5;
#pragma unroll
    for (int r = 0; r < 4; ++r)
        tile[ty + 8*r][tx] = src[(size_t)(bi*32 + ty + 8*r) * DIM + bj*32 + tx];
    __syncthreads();
#pragma unroll
    for (int r = 0; r < 4; ++r)
        dst[(size_t)(bj*32 + ty + 8*r) * DIM + bi*32 + tx] = (f16)tile[tx][ty + 8*r];
}

// ---------- prep: alpha = softmax(x@gate_w + gate_b); xh = fp16(x) ----------
__global__ __launch_bounds__(256) void gate_kernel(
    const float* __restrict__ x, const float* __restrict__ gw,
    const float* __restrict__ gb, float* __restrict__ alpha,
    f16* __restrict__ xh)
{
    int tid = threadIdx.x, lane = tid & 63, wid = tid >> 6;
    int row = blockIdx.x * 4 + wid;
    const float* xr = x + (size_t)row * DIM;
    float acc[8] = {0,0,0,0,0,0,0,0};
    float xv[8];
#pragma unroll
    for (int j = 0; j < 8; ++j) {
        int d = lane + 64*j;
        float v = xr[d];
        xv[j] = v;
        const float4* g = (const float4*)(gw + (size_t)d * 8);
        float4 g0 = g[0], g1 = g[1];
        acc[0] += v*g0.x; acc[1] += v*g0.y; acc[2] += v*g0.z; acc[3] += v*g0.w;
        acc[4] += v*g1.x; acc[5] += v*g1.y; acc[6] += v*g1.z; acc[7] += v*g1.w;
    }
#pragma unroll
    for (int mlane = 32; mlane >= 1; mlane >>= 1) {
#pragma unroll
        for (int k = 0; k < 8; ++k) acc[k] += __shfl_xor(acc[k], mlane, 64);
    }
#pragma unroll
    for (int k = 0; k < 8; ++k) acc[k] += gb[k];
    float mx = acc[0];
#pragma unroll
    for (int k = 1; k < 8; ++k) mx = fmaxf(mx, acc[k]);
    float s = 0.f;
#pragma unroll
    for (int k = 0; k < 8; ++k) { acc[k] = __expf(acc[k] - mx); s += acc[k]; }
    float inv = 1.0f / s;
    if (lane == 0) {
        float4 a0 = {acc[0]*inv, acc[1]*inv, acc[2]*inv, acc[3]*inv};
        float4 a1 = {acc[4]*inv, acc[5]*inv, acc[6]*inv, acc[7]*inv};
        *(float4*)(alpha + (size_t)row*8)     = a0;
        *(float4*)(alpha + (size_t)row*8 + 4) = a1;
    }
#pragma unroll
    for (int j = 0; j < 8; ++j)
        xh[(size_t)row * DIM + lane + 64*j] = (f16)xv[j];
}

// ---------- fused MoIE layer as one M=16384,N=512,K=4096 GEMM ----------
// Paired phases (2 tiles per barrier/vmcnt = 64 sync pts) with R11's
// publish discipline restored: ring-6 B slots, stage distance 3 pairs,
// UNIFORM vmcnt(4) per pair -> every read at pair P has its stages
// drained at wait(P-1) and published by barrier(P-1). (R17's ring-4
// pairing drained in the SAME phase as the read -> race, absmax 18.)
// Same bf regs both halves + sched_barrier(0) pin -> live set = 128.
// Stages post-both-MFMA-groups -> WAR margin >500cyc.

#define READ_BF(SLOT) \
      bf0 = *(const f16x8*)(Ball + (SLOT)*4096 + bOff); \
      bf1 = *(const f16x8*)(Ball + (SLOT)*4096 + bOff + 512); \
      bf2 = *(const f16x8*)(Ball + (SLOT)*4096 + bOff + 1024); \
      bf3 = *(const f16x8*)(Ball + (SLOT)*4096 + bOff + 1536);

#define READ_AF(P) \
      af0 = *(const f16x8*)((P) + aOff); \
      af1 = *(const f16x8*)((P) + aOff + 512); \
      af2 = *(const f16x8*)((P) + aOff + 1024); \
      af3 = *(const f16x8*)((P) + aOff + 1536);

#define MULS(E) { \
      f16 s0_ = salh0[E], s1_ = salh1[E], s2_ = salh2[E], s3_ = salh3[E]; \
      a0 = af0 * (f16x8){s0_,s0_,s0_,s0_,s0_,s0_,s0_,s0_}; \
      a1 = af1 * (f16x8){s1_,s1_,s1_,s1_,s1_,s1_,s1_,s1_}; \
      a2 = af2 * (f16x8){s2_,s2_,s2_,s2_,s2_,s2_,s2_,s2_}; \
      a3 = af3 * (f16x8){s3_,s3_,s3_,s3_,s3_,s3_,s3_,s3_}; }

#define MFMAS() \
      __builtin_amdgcn_s_setprio(1); \
      acc[0][0]=MFMA16(a0,bf0,acc[0][0]); acc[0][1]=MFMA16(a0,bf1,acc[0][1]); \
      acc[0][2]=MFMA16(a0,bf2,acc[0][2]); acc[0][3]=MFMA16(a0,bf3,acc[0][3]); \
      acc[1][0]=MFMA16(a1,bf0,acc[1][0]); acc[1][1]=MFMA16(a1,bf1,acc[1][1]); \
      acc[1][2]=MFMA16(a1,bf2,acc[1][2]); acc[1][3]=MFMA16(a1,bf3,acc[1][3]); \
      acc[2][0]=MFMA16(a2,bf0,acc[2][0]); acc[2][1]=MFMA16(a2,bf1,acc[2][1]); \
      acc[2][2]=MFMA16(a2,bf2,acc[2][2]); acc[2][3]=MFMA16(a2,bf3,acc[2][3]); \
      acc[3][0]=MFMA16(a3,bf0,acc[3][0]); acc[3][1]=MFMA16(a3,bf1,acc[3][1]); \
      acc[3][2]=MFMA16(a3,bf2,acc[3][2]); acc[3][3]=MFMA16(a3,bf3,acc[3][3]); \
      __builtin_amdgcn_s_setprio(0);

// B-tile stage: two 4KB halves (rows 0-63, 64-127)
#define STG_B(KS, EXP, SLOT) \
      GLOAD16(bSrc + (size_t)(EXP)*WSTRIDE + (KS)*BK,          bD + (SLOT)*4096); \
      GLOAD16(bSrc + (size_t)(EXP)*WSTRIDE + (KS)*BK + 64*DIM, bD + (SLOT)*4096 + 2048);
#define STG_A(KS, DST) \
      GLOAD16(aSrc + (KS)*BK,          DST); \
      GLOAD16(aSrc + (KS)*BK + 64*DIM, DST + 2048);

// generic pair: wait(4); read tile0 pre-BAR; BAR; MFMA; [pin] read tile1
// into SAME regs; MFMA; stage (post both groups).
#define PAIR(WAITN, S0, E0, S1, E1, ISSUE) \
    asm volatile("s_waitcnt vmcnt(" #WAITN ")" ::: "memory"); \
    READ_BF(S0) \
    MULS(E0) \
    __builtin_amdgcn_s_barrier(); \
    MFMAS() \
    __builtin_amdgcn_sched_barrier(0); \
    READ_BF(S1) \
    MULS(E1) \
    MFMAS() \
    ISSUE

// first pair of ss: af re-read pre-BAR; MULS(0) post-BAR (af dep)
#define PAIR0(WAITN, ARD, S0, S1, ISSUE) \
    asm volatile("s_waitcnt vmcnt(" #WAITN ")" ::: "memory"); \
    READ_AF(ARD); \
    READ_BF(S0) \
    __builtin_amdgcn_s_barrier(); \
    MULS(0) \
    MFMAS() \
    __builtin_amdgcn_sched_barrier(0); \
    READ_BF(S1) \
    MULS(1) \
    MFMAS() \
    ISSUE

// one ss = 4 pairs; B0..B5 = slots (8*SS+0..5) mod 6 (pair3 reads B0,B1)
#define SSBODY(SS, B0,B1,B2,B3,B4,B5) { \
      const f16* Ard = ((SS) & 1) ? Abuf[1] : Abuf[0]; \
      f16* an = ((SS) & 1) ? aW0 : aW1; \
      PAIR0(4, Ard, B0, B1,  { STG_B(SS, 6, B0); STG_B(SS, 7, B1); }) \
      PAIR(4, B2, 2, B3, 3,  { STG_B((SS)+1, 0, B2); STG_B((SS)+1, 1, B3); \
                               STG_A((SS)+1, an); }) \
      PAIR(4, B4, 4, B5, 5,  { STG_B((SS)+1, 2, B4); STG_B((SS)+1, 3, B5); }) \
      PAIR(4, B0, 6, B1, 7,  { STG_B((SS)+1, 4, B0); STG_B((SS)+1, 5, B1); }) }

template<int RELU, int OUTF32>
__global__ __launch_bounds__(256, 2) void moie_gemm(
    const f16*  __restrict__ A,      // [16384][512] fp16
    const f16*  __restrict__ Wt,     // [8][512 o][512 i] fp16 (this layer)
    const float* __restrict__ alpha, // [16384][8]
    const float* __restrict__ bias,  // [8][512]
    f16*  __restrict__ Hout,
    float* __restrict__ Fout)
{
    __shared__ __align__(16) f16 Abuf[2][BM*BK];   // 2 x 8KB
    __shared__ __align__(16) f16 Bbuf[6][BN*BK];   // 6 x 8KB ring
    __shared__ float alpha_s[BM*9];                // 4.6KB
    __shared__ float bias_s[NEXP*BN];              // 4KB  -> ~72.6KB total

    // 512 blocks; bid&7 = XCD; 64 consecutive swz per XCD -> fixed cb panel per XCD L2
    int bid = blockIdx.x;
    int swz = (bid & 7) * 64 + (bid >> 3);
    int cb = swz >> 7, rb = swz & 127;
    int rowBase = rb * BM, colBase = cb * BN;
    int tid = threadIdx.x, lane = tid & 63, wid = tid >> 6;
    int wm = wid >> 1, wn = wid & 1;     // 2x2 waves, wave tile 64x64

    for (int i = tid; i < BM*NEXP; i += 256)
        alpha_s[(i >> 3)*9 + (i & 7)] = alpha[(size_t)(rowBase + (i >> 3))*8 + (i & 7)];
    for (int i = tid; i < NEXP*BN; i += 256)
        bias_s[i] = bias[(i >> 7)*DIM + colBase + (i & 127)];

    // staging: thread t -> row t>>2 (+64 second half), slot t&3;
    // LDS slot g holds granule g^((row>>1)&3) (R5-verified conflict-free)
    int srow = tid >> 2;
    int sg   = ((tid & 3) ^ ((srow >> 1) & 3)) * 8;
    const f16* aSrc = A  + (size_t)(rowBase + srow) * DIM + sg;
    const f16* bSrc = Wt + (size_t)(colBase + srow) * DIM + sg;
    f16* aW0 = Abuf[0] + tid*8;
    f16* aW1 = Abuf[1] + tid*8;
    f16* bD  = Bbuf[0] + tid*8;
    const f16* Ball = Bbuf[0];

    int kg   = ((lane >> 4) ^ (((lane & 15) >> 1) & 3)) * 8;
    int aOff = (wm*64 + (lane & 15)) * BK + kg;
    int bOff = (wn*64 + (lane & 15)) * BK + kg;

    __syncthreads();   // alpha_s/bias_s ready (full drain of their loads)

    // prologue (14 loads): A0(2), B tiles (0,0..5) -> slots 0..5 (12)
    STG_A(0, aW0);
    STG_B(0, 0, 0); STG_B(0, 1, 1); STG_B(0, 2, 2);
    STG_B(0, 3, 3); STG_B(0, 4, 4); STG_B(0, 5, 5);

    f16 salh0[NEXP], salh1[NEXP], salh2[NEXP], salh3[NEXP];
    {
        int r0 = wm*64 + (lane & 15);
#pragma unroll
        for (int e = 0; e < NEXP; ++e) {
            salh0[e] = (f16)alpha_s[(r0     )*9 + e];
            salh1[e] = (f16)alpha_s[(r0 + 16)*9 + e];
            salh2[e] = (f16)alpha_s[(r0 + 32)*9 + e];
            salh3[e] = (f16)alpha_s[(r0 + 48)*9 + e];
        }
    }

    f16x8 af0, af1, af2, af3, a0, a1, a2, a3, bf0, bf1, bf2, bf3;
    f32x4 acc[4][4];
#pragma unroll
    for (int i = 0; i < 4; ++i)
#pragma unroll
        for (int j = 0; j < 4; ++j) acc[i][j] = (f32x4){0.f,0.f,0.f,0.f};

    // prologue gate: A0 + T0 + T1 drained (leaves T2..T5 = 8), published
    WAITV(8); __builtin_amdgcn_s_barrier();

    // ss = 0..14 in groups of 3 (slot base (8*ss)%6 cycles 0,2,4)
    for (int ss = 0; ss < NKS - 1; ss += 3) {
        SSBODY(ss,     0,1,2,3,4,5)
        SSBODY(ss + 1, 2,3,4,5,0,1)
        SSBODY(ss + 2, 4,5,0,1,2,3)
    }
    {   // tail ss = 15 (slot base 0): waits [4,4,0,0]; stages end at (15,7)
        PAIR0(4, Abuf[1], 0, 1, { STG_B(15, 6, 0); STG_B(15, 7, 1); })
        PAIR(4, 2, 2, 3, 3,     { })
        PAIR(0, 4, 4, 5, 5,     { })
        PAIR(0, 0, 6, 1, 7,     { })
    }

    // epilogue: + sum_e alpha*bias, relu, store
#pragma unroll
    for (int i = 0; i < 4; ++i)
#pragma unroll
        for (int q = 0; q < 4; ++q) {
            int rloc = wm*64 + i*16 + (lane >> 4)*4 + q;
            size_t row = (size_t)(rowBase + rloc);
#pragma unroll
            for (int j = 0; j < 4; ++j) {
                int cloc = wn*64 + j*16 + (lane & 15);
                float v = acc[i][j][q];
#pragma unroll
                for (int e2 = 0; e2 < NEXP; ++e2)
                    v += alpha_s[rloc*9 + e2] * bias_s[e2*BN + cloc];
                if (RELU) v = fmaxf(v, 0.f);
                if (OUTF32) Fout[row*DIM + colBase + cloc] = v;
                else        Hout[row*DIM + colBase + cloc] = (f16)v;
            }
        }
}

extern "C" void kernel_launch(void* const* d_in, const int* in_sizes, int n_in,
                              void* d_out, int out_size, void* d_ws, size_t ws_size,
                              hipStream_t stream)
{
    const float* x  = (const float*)d_in[0];
    const float* gw = (const float*)d_in[1];
    const float* gb = (const float*)d_in[2];
    const float* w0 = (const float*)d_in[3];
    const float* b0 = (const float*)d_in[4];
    const float* w1 = (const float*)d_in[5];
    const float* b1 = (const float*)d_in[6];
    const float* w2 = (const float*)d_in[7];
    const float* b2 = (const float*)d_in[8];
    const float* wo = (const float*)d_in[9];
    const float* bo = (const float*)d_in[10];
    float* out = (float*)d_out;

    char* ws = (char*)d_ws;
    const size_t wtBytes = (size_t)4 * NEXP * DIM * DIM * sizeof(f16);
    f16*   Wt    = (f16*)ws;
    float* alpha = (float*)(ws + wtBytes);
    f16*   h0    = (f16*)(ws + wtBytes + (size_t)NROWS*NEXP*sizeof(float));
    f16*   h1    = h0 + (size_t)NROWS * DIM;
    const size_t L = (size_t)NEXP * DIM * DIM;

    convert_w<<<8192, 256, 0, stream>>>(w0, w1, w2, wo, Wt);
    gate_kernel<<<NROWS/4, 256, 0, stream>>>(x, gw, gb, alpha, h0);

    moie_gemm<1,0><<<512, 256, 0, stream>>>(h0, Wt,       alpha, b0, h1, nullptr);
    moie_gemm<1,0><<<512, 256, 0, stream>>>(h1, Wt + L,   alpha, b1, h0, nullptr);
    moie_gemm<1,0><<<512, 256, 0, stream>>>(h0, Wt + 2*L, alpha, b2, h1, nullptr);
    moie_gemm<0,1><<<512, 256, 0, stream>>>(h1, Wt + 3*L, alpha, bo, nullptr, out);
}

// Round 19
// 312.361 us; speedup vs baseline: 6.6365x; 6.6365x over previous
//
#include <hip/hip_runtime.h>
#include <stdint.h>

typedef _Float16 f16;
typedef _Float16 f16x8 __attribute__((ext_vector_type(8)));
typedef float f32x4 __attribute__((ext_vector_type(4)));

#define NROWS 16384
#define DIM   512
#define NEXP  8
#define BM    128
#define BN    128
#define BK    32
#define NKS   16
#define WSTRIDE (DIM*DIM)

#define GLOAD16(gp, lp) __builtin_amdgcn_global_load_lds( \
    (const __attribute__((address_space(1))) void*)(gp),  \
    (__attribute__((address_space(3))) void*)(lp), 16, 0, 0)

#define MFMA16(a,b,c) __builtin_amdgcn_mfma_f32_16x16x32_f16(a, b, c, 0, 0, 0)

#define WAITV(N) asm volatile("s_waitcnt vmcnt(" #N ")" ::: "memory")

// ---------- prep: W[l][e][i][o] fp32 -> Wt[l][e][o][i] fp16 ----------
__global__ __launch_bounds__(256) void convert_w(
    const float* __restrict__ w0, const float* __restrict__ w1,
    const float* __restrict__ w2, const float* __restrict__ wo,
    f16* __restrict__ Wt)
{
    __shared__ float tile[32][33];
    int b  = blockIdx.x;
    int m  = b >> 8;
    int bi = (b >> 4) & 15;
    int bj = b & 15;
    int layer = m >> 3;
    const float* src =
        (layer == 0 ? w0 : layer == 1 ? w1 : layer == 2 ? w2 : wo)
        + (size_t)(m & 7) * DIM * DIM;
    f16* dst = Wt + (size_t)m * DIM * DIM;
    int tx = threadIdx.x & 31, ty = threadIdx.x >> 5;
#pragma unroll
    for (int r = 0; r < 4; ++r)
        tile[ty + 8*r][tx] = src[(size_t)(bi*32 + ty + 8*r) * DIM + bj*32 + tx];
    __syncthreads();
#pragma unroll
    for (int r = 0; r < 4; ++r)
        dst[(size_t)(bj*32 + ty + 8*r) * DIM + bi*32 + tx] = (f16)tile[tx][ty + 8*r];
}

// ---------- prep: alpha = softmax(x@gate_w + gate_b); xh = fp16(x) ----------
__global__ __launch_bounds__(256) void gate_kernel(
    const float* __restrict__ x, const float* __restrict__ gw,
    const float* __restrict__ gb, float* __restrict__ alpha,
    f16* __restrict__ xh)
{
    int tid = threadIdx.x, lane = tid & 63, wid = tid >> 6;
    int row = blockIdx.x * 4 + wid;
    const float* xr = x + (size_t)row * DIM;
    float acc[8] = {0,0,0,0,0,0,0,0};
    float xv[8];
#pragma unroll
    for (int j = 0; j < 8; ++j) {
        int d = lane + 64*j;
        float v = xr[d];
        xv[j] = v;
        const float4* g = (const float4*)(gw + (size_t)d * 8);
        float4 g0 = g[0], g1 = g[1];
        acc[0] += v*g0.x; acc[1] += v*g0.y; acc[2] += v*g0.z; acc[3] += v*g0.w;
        acc[4] += v*g1.x; acc[5] += v*g1.y; acc[6] += v*g1.z; acc[7] += v*g1.w;
    }
#pragma unroll
    for (int mlane = 32; mlane >= 1; mlane >>= 1) {
#pragma unroll
        for (int k = 0; k < 8; ++k) acc[k] += __shfl_xor(acc[k], mlane, 64);
    }
#pragma unroll
    for (int k = 0; k < 8; ++k) acc[k] += gb[k];
    float mx = acc[0];
#pragma unroll
    for (int k = 1; k < 8; ++k) mx = fmaxf(mx, acc[k]);
    float s = 0.f;
#pragma unroll
    for (int k = 0; k < 8; ++k) { acc[k] = __expf(acc[k] - mx); s += acc[k]; }
    float inv = 1.0f / s;
    if (lane == 0) {
        float4 a0 = {acc[0]*inv, acc[1]*inv, acc[2]*inv, acc[3]*inv};
        float4 a1 = {acc[4]*inv, acc[5]*inv, acc[6]*inv, acc[7]*inv};
        *(float4*)(alpha + (size_t)row*8)     = a0;
        *(float4*)(alpha + (size_t)row*8 + 4) = a1;
    }
#pragma unroll
    for (int j = 0; j < 8; ++j)
        xh[(size_t)row * DIM + lane + 64*j] = (f16)xv[j];
}

// ---------- fused MoIE layer as one M=16384,N=512,K=4096 GEMM ----------
// R11 FINAL (verified best, reproduced twice at 312 us):
// - alpha folded into A-frags per (ks,e): C = Atilde @ Wtilde in ONE GEMM
// - ks outer / experts inner: A staged once per 8 tiles (8x A-traffic cut)
// - global_load_lds dwordx4 staging, B ring-4 + A dbuf, counted per-phase
//   vmcnt (paces DMA; publish: drain at wait(P-1), barrier(P-1), read at P)
// - read-hoist: ds_reads pre-barrier, latency drains during sync
// - conflict-free LDS granule swizzle: slot = q ^ ((row>>1)&3)
// - VGPR=128 exactly (the occupancy step), 2 blocks/CU, grid 512 XCD-swz.
// Failed escalations (do NOT retry): reg double-buffer (spills: R8/R9/R10),
// 4 blocks/CU (R12), group vmcnt waits (race: R13-15), paired phases
// (race R17 / spill R18). Family ceiling ~79 us/GEMM = m97-class ~900 TF.

#define READ_BF(SLOT) \
      bf0 = *(const f16x8*)(Ball + (SLOT)*4096 + bOff); \
      bf1 = *(const f16x8*)(Ball + (SLOT)*4096 + bOff + 512); \
      bf2 = *(const f16x8*)(Ball + (SLOT)*4096 + bOff + 1024); \
      bf3 = *(const f16x8*)(Ball + (SLOT)*4096 + bOff + 1536);

#define READ_AF(P) \
      af0 = *(const f16x8*)((P) + aOff); \
      af1 = *(const f16x8*)((P) + aOff + 512); \
      af2 = *(const f16x8*)((P) + aOff + 1024); \
      af3 = *(const f16x8*)((P) + aOff + 1536);

#define MULS(E) { \
      f16 s0_ = salh0[E], s1_ = salh1[E], s2_ = salh2[E], s3_ = salh3[E]; \
      a0 = af0 * (f16x8){s0_,s0_,s0_,s0_,s0_,s0_,s0_,s0_}; \
      a1 = af1 * (f16x8){s1_,s1_,s1_,s1_,s1_,s1_,s1_,s1_}; \
      a2 = af2 * (f16x8){s2_,s2_,s2_,s2_,s2_,s2_,s2_,s2_}; \
      a3 = af3 * (f16x8){s3_,s3_,s3_,s3_,s3_,s3_,s3_,s3_}; }

#define MFMAS() \
      __builtin_amdgcn_s_setprio(1); \
      acc[0][0]=MFMA16(a0,bf0,acc[0][0]); acc[0][1]=MFMA16(a0,bf1,acc[0][1]); \
      acc[0][2]=MFMA16(a0,bf2,acc[0][2]); acc[0][3]=MFMA16(a0,bf3,acc[0][3]); \
      acc[1][0]=MFMA16(a1,bf0,acc[1][0]); acc[1][1]=MFMA16(a1,bf1,acc[1][1]); \
      acc[1][2]=MFMA16(a1,bf2,acc[1][2]); acc[1][3]=MFMA16(a1,bf3,acc[1][3]); \
      acc[2][0]=MFMA16(a2,bf0,acc[2][0]); acc[2][1]=MFMA16(a2,bf1,acc[2][1]); \
      acc[2][2]=MFMA16(a2,bf2,acc[2][2]); acc[2][3]=MFMA16(a2,bf3,acc[2][3]); \
      acc[3][0]=MFMA16(a3,bf0,acc[3][0]); acc[3][1]=MFMA16(a3,bf1,acc[3][1]); \
      acc[3][2]=MFMA16(a3,bf2,acc[3][2]); acc[3][3]=MFMA16(a3,bf3,acc[3][3]); \
      __builtin_amdgcn_s_setprio(0);

// B-tile stage: two 4KB halves (rows 0-63, 64-127)
#define STG_B(KS, EXP, SLOT) \
      GLOAD16(bSrc + (size_t)(EXP)*WSTRIDE + (KS)*BK,          bD + (SLOT)*4096); \
      GLOAD16(bSrc + (size_t)(EXP)*WSTRIDE + (KS)*BK + 64*DIM, bD + (SLOT)*4096 + 2048);
#define STG_A(KS, DST) \
      GLOAD16(aSrc + (KS)*BK,          DST); \
      GLOAD16(aSrc + (KS)*BK + 64*DIM, DST + 2048);

// generic phase (e1..e7): wait; READ pre-BAR; MULS pre-BAR; BAR; MFMA; stage
#define PHX(WAITN, SLOT, E, ISSUE) \
    asm volatile("s_waitcnt vmcnt(" #WAITN ")" ::: "memory"); \
    READ_BF(SLOT) \
    MULS(E) \
    __builtin_amdgcn_s_barrier(); \
    MFMAS() \
    ISSUE

// e0 phase: also re-reads af (fresh ss) pre-BAR; MULS after BAR (af dep)
#define PH0(WAITN, ARD, ISSUE) \
    asm volatile("s_waitcnt vmcnt(" #WAITN ")" ::: "memory"); \
    READ_AF(ARD); \
    READ_BF(0) \
    __builtin_amdgcn_s_barrier(); \
    MULS(0) \
    MFMAS() \
    ISSUE

template<int RELU, int OUTF32>
__global__ __launch_bounds__(256, 2) void moie_gemm(
    const f16*  __restrict__ A,      // [16384][512] fp16
    const f16*  __restrict__ Wt,     // [8][512 o][512 i] fp16 (this layer)
    const float* __restrict__ alpha, // [16384][8]
    const float* __restrict__ bias,  // [8][512]
    f16*  __restrict__ Hout,
    float* __restrict__ Fout)
{
    __shared__ __align__(16) f16 Abuf[2][BM*BK];   // 2 x 8KB
    __shared__ __align__(16) f16 Bbuf[4][BN*BK];   // 4 x 8KB ring
    __shared__ float alpha_s[BM*9];
    __shared__ float bias_s[NEXP*BN];

    // 512 blocks; bid&7 = XCD; 64 consecutive swz per XCD -> fixed cb panel per XCD L2
    int bid = blockIdx.x;
    int swz = (bid & 7) * 64 + (bid >> 3);
    int cb = swz >> 7, rb = swz & 127;
    int rowBase = rb * BM, colBase = cb * BN;
    int tid = threadIdx.x, lane = tid & 63, wid = tid >> 6;
    int wm = wid >> 1, wn = wid & 1;     // 2x2 waves, wave tile 64x64

    for (int i = tid; i < BM*NEXP; i += 256)
        alpha_s[(i >> 3)*9 + (i & 7)] = alpha[(size_t)(rowBase + (i >> 3))*8 + (i & 7)];
    for (int i = tid; i < NEXP*BN; i += 256)
        bias_s[i] = bias[(i >> 7)*DIM + colBase + (i & 127)];

    // staging: thread t -> row t>>2 (+64 second half), slot t&3;
    // LDS slot g holds granule g^((row>>1)&3) (R5-verified conflict-free)
    int srow = tid >> 2;
    int sg   = ((tid & 3) ^ ((srow >> 1) & 3)) * 8;
    const f16* aSrc = A  + (size_t)(rowBase + srow) * DIM + sg;
    const f16* bSrc = Wt + (size_t)(colBase + srow) * DIM + sg;
    f16* aW0 = Abuf[0] + tid*8;
    f16* aW1 = Abuf[1] + tid*8;
    f16* bD  = Bbuf[0] + tid*8;
    const f16* Ball = Bbuf[0];

    int kg   = ((lane >> 4) ^ (((lane & 15) >> 1) & 3)) * 8;
    int aOff = (wm*64 + (lane & 15)) * BK + kg;
    int bOff = (wn*64 + (lane & 15)) * BK + kg;

    __syncthreads();   // alpha_s/bias_s ready (full drain of their loads)

    // prologue queue (10): A0(2), B tiles 0..3 -> slots 0..3 (8)
    STG_A(0, aW0);
    STG_B(0, 0, 0); STG_B(0, 1, 1); STG_B(0, 2, 2); STG_B(0, 3, 3);

    f16 salh0[NEXP], salh1[NEXP], salh2[NEXP], salh3[NEXP];
    {
        int r0 = wm*64 + (lane & 15);
#pragma unroll
        for (int e = 0; e < NEXP; ++e) {
            salh0[e] = (f16)alpha_s[(r0     )*9 + e];
            salh1[e] = (f16)alpha_s[(r0 + 16)*9 + e];
            salh2[e] = (f16)alpha_s[(r0 + 32)*9 + e];
            salh3[e] = (f16)alpha_s[(r0 + 48)*9 + e];
        }
    }

    f16x8 af0, af1, af2, af3, a0, a1, a2, a3, bf0, bf1, bf2, bf3;
    f32x4 acc[4][4];
#pragma unroll
    for (int i = 0; i < 4; ++i)
#pragma unroll
        for (int j = 0; j < 4; ++j) acc[i][j] = (f32x4){0.f,0.f,0.f,0.f};

    // prologue sync: A0 + B(slot0) drained across all waves, published
    WAITV(4); __builtin_amdgcn_s_barrier();

    for (int ss = 0; ss < NKS - 1; ++ss) {
        const f16* Ard = (ss & 1) ? Abuf[1] : Abuf[0];
        f16* an = (ss & 1) ? aW0 : aW1;
        // waits (FIFO-derived, pre-read safety): [4,6,6,4,4,4,4,4]
        PH0(4, Ard, { STG_B(ss, 4, 0); STG_A(ss + 1, an); })
        PHX(6, 1, 1, { STG_B(ss, 5, 1); })
        PHX(6, 2, 2, { STG_B(ss, 6, 2); })
        PHX(4, 3, 3, { STG_B(ss, 7, 3); })
        PHX(4, 0, 4, { STG_B(ss + 1, 0, 0); })
        PHX(4, 1, 5, { STG_B(ss + 1, 1, 1); })
        PHX(4, 2, 6, { STG_B(ss + 1, 2, 2); })
        PHX(4, 3, 7, { STG_B(ss + 1, 3, 3); })
    }
    {   // tail ss = 15 (no A-stage at e0 -> waits [4,4,4,4,4,2,0,0])
        PH0(4, Abuf[1], { STG_B(15, 4, 0); })
        PHX(4, 1, 1, { STG_B(15, 5, 1); })
        PHX(4, 2, 2, { STG_B(15, 6, 2); })
        PHX(4, 3, 3, { STG_B(15, 7, 3); })
        PHX(4, 0, 4, { })
        PHX(2, 1, 5, { })
        PHX(0, 2, 6, { })
        PHX(0, 3, 7, { })
    }

    // epilogue: + sum_e alpha*bias, relu, store
#pragma unroll
    for (int i = 0; i < 4; ++i)
#pragma unroll
        for (int q = 0; q < 4; ++q) {
            int rloc = wm*64 + i*16 + (lane >> 4)*4 + q;
            size_t row = (size_t)(rowBase + rloc);
#pragma unroll
            for (int j = 0; j < 4; ++j) {
                int cloc = wn*64 + j*16 + (lane & 15);
                float v = acc[i][j][q];
#pragma unroll
                for (int e2 = 0; e2 < NEXP; ++e2)
                    v += alpha_s[rloc*9 + e2] * bias_s[e2*BN + cloc];
                if (RELU) v = fmaxf(v, 0.f);
                if (OUTF32) Fout[row*DIM + colBase + cloc] = v;
                else        Hout[row*DIM + colBase + cloc] = (f16)v;
            }
        }
}

extern "C" void kernel_launch(void* const* d_in, const int* in_sizes, int n_in,
                              void* d_out, int out_size, void* d_ws, size_t ws_size,
                              hipStream_t stream)
{
    const float* x  = (const float*)d_in[0];
    const float* gw = (const float*)d_in[1];
    const float* gb = (const float*)d_in[2];
    const float* w0 = (const float*)d_in[3];
    const float* b0 = (const float*)d_in[4];
    const float* w1 = (const float*)d_in[5];
    const float* b1 = (const float*)d_in[6];
    const float* w2 = (const float*)d_in[7];
    const float* b2 = (const float*)d_in[8];
    const float* wo = (const float*)d_in[9];
    const float* bo = (const float*)d_in[10];
    float* out = (float*)d_out;

    char* ws = (char*)d_ws;
    const size_t wtBytes = (size_t)4 * NEXP * DIM * DIM * sizeof(f16);
    f16*   Wt    = (f16*)ws;
    float* alpha = (float*)(ws + wtBytes);
    f16*   h0    = (f16*)(ws + wtBytes + (size_t)NROWS*NEXP*sizeof(float));
    f16*   h1    = h0 + (size_t)NROWS * DIM;
    const size_t L = (size_t)NEXP * DIM * DIM;

    convert_w<<<8192, 256, 0, stream>>>(w0, w1, w2, wo, Wt);
    gate_kernel<<<NROWS/4, 256, 0, stream>>>(x, gw, gb, alpha, h0);

    moie_gemm<1,0><<<512, 256, 0, stream>>>(h0, Wt,       alpha, b0, h1, nullptr);
    moie_gemm<1,0><<<512, 256, 0, stream>>>(h1, Wt + L,   alpha, b1, h0, nullptr);
    moie_gemm<1,0><<<512, 256, 0, stream>>>(h0, Wt + 2*L, alpha, b2, h1, nullptr);
    moie_gemm<0,1><<<512, 256, 0, stream>>>(h1, Wt + 3*L, alpha, bo, nullptr, out);
}